// Round 14
// baseline (353.435 us; speedup 1.0000x reference)
//
#include <hip/hip_runtime.h>
#include <stdint.h>

typedef __attribute__((ext_vector_type(8))) short short8;
typedef __attribute__((ext_vector_type(4))) float floatx4;
typedef __attribute__((ext_vector_type(16))) float f32x16;
typedef __attribute__((ext_vector_type(4))) unsigned int uint4v;

#define NSEQ 8
#define BLKSZ 16
#define NBLK_PER_SEQ 128
#define HQN 32
#define HKVN 8
#define GQ 4
#define HD 128
#define WINDOW 1024
// SCALE * log2(e): softmax in exp2 domain
#define QSCALE 0.12751744f

#define QB 32       // q rows per block
#define KVG 64      // kv per wave-group per iteration
#define KROW 136    // K lds row stride (bf16), [128][136]
#define VROW 136    // V^T lds col stride, [128][136]

#define MFMA32 __builtin_amdgcn_mfma_f32_32x32x16_bf16

// two f32 -> packed bf16x2 (round-half-up); low16 = lo, high16 = hi
static __device__ __forceinline__ unsigned int pack2bf(float lo, float hi) {
    unsigned int a = __builtin_bit_cast(unsigned int, lo) + 0x8000u;
    unsigned int b = __builtin_bit_cast(unsigned int, hi) + 0x8000u;
    return __builtin_amdgcn_perm(b, a, 0x07060302u);
}

extern __shared__ char smem[];   // 69632 B: K [128][136] | V^T [128][136]

__global__ __launch_bounds__(512, 4)
void attn_fwd(const float* __restrict__ qg,
              const float* __restrict__ kg,
              const float* __restrict__ vg,
              const int* __restrict__ bt,
              const int* __restrict__ seqlens,
              const int* __restrict__ qsl,
              float* __restrict__ outg)
{
    short (*Klds)[KROW] = (short(*)[KROW])smem;
    short (*Vt)[VROW]   = (short(*)[VROW])(smem + 34816);

    const int tid  = threadIdx.x;
    const int lane = tid & 63;
    const int wave = tid >> 6;        // 0..7
    const int hb   = tid >> 8;        // kv-split group 0/1
    const int t8   = tid & 255;      // index within half-block
    const int l31  = lane & 31;
    const int hi   = lane >> 5;

    // XCD pinning: b&7 = kv head
    const int b  = blockIdx.x;
    const int h  = b & 7;
    const int qt = (b >> 3) & 7;
    const int s  = b >> 6;
    const int q0 = qt * QB;

    const int qstart = qsl[s];
    const int numq   = qsl[s + 1] - qstart;
    const int slen   = seqlens[s];
    const int ctx    = slen - numq;
    const int hq     = h * GQ + (wave & 3);

    // ---- Q fragments (B-operand 32x32x16: col=q=l31, k=ks*16+hi*8+j), pre-scaled ----
    short8 qf[8];
    {
        const float* qrow = qg + ((size_t)(qstart + q0 + l31) * HQN + hq) * HD;
        #pragma unroll
        for (int ks = 0; ks < 8; ++ks) {
            floatx4 f0 = *(const floatx4*)(qrow + ks * 16 + hi * 8);
            floatx4 f1 = *(const floatx4*)(qrow + ks * 16 + hi * 8 + 4);
            uint4v w;
            w[0] = pack2bf(f0[0] * QSCALE, f0[1] * QSCALE);
            w[1] = pack2bf(f0[2] * QSCALE, f0[3] * QSCALE);
            w[2] = pack2bf(f1[0] * QSCALE, f1[1] * QSCALE);
            w[3] = pack2bf(f1[2] * QSCALE, f1[3] * QSCALE);
            qf[ks] = __builtin_bit_cast(short8, w);
        }
    }

    // O^T accumulators: lane q = l31, d = dblk*32 + (r&3) + 8*(r>>2) + 4*hi
    f32x16 oacc[4];
    #pragma unroll
    for (int dblk = 0; dblk < 4; ++dblk)
        #pragma unroll
        for (int i = 0; i < 16; ++i)
            oacc[dblk][i] = 0.f;

    float mrun = -INFINITY, lrun = 0.f;   // log2 units, per kv-group

    int lo = ctx + q0 - WINDOW + 1; if (lo < 0) lo = 0;
    int hiq = ctx + q0 + QB - 1;    if (hiq > slen - 1) hiq = slen - 1;
    const int t0 = lo >> 7, t1 = hiq >> 7;   // 128-kv block tiles

    // staging maps (within half-block; group stages its own kv-half)
    const int srow  = t8 >> 3;          // K: kv row 0..31 (+32 for p=1)
    const int sd0   = (t8 & 7) * 16;    // K: d offset (floats)
    const int k2    = t8 & 15;          // V: kv pair index
    const int d0v   = (t8 >> 4) * 8;    // V: d offset (0..120)
    const int kbase = hb * KVG;         // kv offset of this group

    floatx4 fk[8], fv[8];

#define LOAD_HALF(kv0_, p) {                                                         \
        const int kvp = (kv0_) + kbase + (p) * 32 + srow;                            \
        const int blk = bt[s * NBLK_PER_SEQ + (kvp >> 4)];                           \
        const float* src = kg + (((size_t)blk * BLKSZ + (kvp & 15)) * HKVN + h) * HD + sd0; \
        fk[(p)*4+0] = *(const floatx4*)(src);                                        \
        fk[(p)*4+1] = *(const floatx4*)(src + 4);                                    \
        fk[(p)*4+2] = *(const floatx4*)(src + 8);                                    \
        fk[(p)*4+3] = *(const floatx4*)(src + 12);                                   \
        const int kvv = (kv0_) + kbase + (p) * 32 + 2 * k2;                          \
        const int blkv = bt[s * NBLK_PER_SEQ + (kvv >> 4)];                          \
        const float* vsrc = vg + (((size_t)blkv * BLKSZ + (kvv & 15)) * HKVN + h) * HD + d0v; \
        fv[(p)*4+0] = *(const floatx4*)(vsrc);                                       \
        fv[(p)*4+1] = *(const floatx4*)(vsrc + 4);                                   \
        fv[(p)*4+2] = *(const floatx4*)(vsrc + (size_t)HKVN * HD);                   \
        fv[(p)*4+3] = *(const floatx4*)(vsrc + (size_t)HKVN * HD + 4);               \
    }
#define LOAD_TILE(kv0_) { LOAD_HALF(kv0_, 0); LOAD_HALF(kv0_, 1); }

    LOAD_TILE(t0 << 7);

    for (int t = t0; t <= t1; ++t) {
        const int kv0g = (t << 7) + kbase;   // this group's compute/staging base

        // ---- convert + store tile (each group stages its kv-half) ----
        #pragma unroll
        for (int p = 0; p < 2; ++p) {
            const int row = kbase + p * 32 + srow;
            uint4v w;
            w[0] = pack2bf(fk[p*4+0][0], fk[p*4+0][1]);
            w[1] = pack2bf(fk[p*4+0][2], fk[p*4+0][3]);
            w[2] = pack2bf(fk[p*4+1][0], fk[p*4+1][1]);
            w[3] = pack2bf(fk[p*4+1][2], fk[p*4+1][3]);
            *(uint4v*)&Klds[row][sd0] = w;
            w[0] = pack2bf(fk[p*4+2][0], fk[p*4+2][1]);
            w[1] = pack2bf(fk[p*4+2][2], fk[p*4+2][3]);
            w[2] = pack2bf(fk[p*4+3][0], fk[p*4+3][1]);
            w[3] = pack2bf(fk[p*4+3][2], fk[p*4+3][3]);
            *(uint4v*)&Klds[row][sd0 + 8] = w;
        }
        #pragma unroll
        for (int p = 0; p < 2; ++p)
            #pragma unroll
            for (int i = 0; i < 8; ++i) {
                *(unsigned int*)&Vt[d0v + i][kbase + p * 32 + 2 * k2] =
                    pack2bf(fv[p*4 + (i >> 2)][i & 3], fv[p*4 + 2 + (i >> 2)][i & 3]);
            }

        // ---- issue next tile's global loads ----
        if (t < t1) LOAD_TILE((t + 1) << 7);

        __syncthreads();   // bar1: staged tile visible

        // ---- swapped QK^T 32x32 on this group's two 32-kv halves ----
        f32x16 sacc0, sacc1;
        #pragma unroll
        for (int i = 0; i < 16; ++i) { sacc0[i] = 0.f; sacc1[i] = 0.f; }
        #pragma unroll
        for (int ks = 0; ks < 8; ++ks) {
            short8 kf0 = *(const short8*)&Klds[kbase + l31][ks * 16 + hi * 8];
            short8 kf1 = *(const short8*)&Klds[kbase + 32 + l31][ks * 16 + hi * 8];
            sacc0 = MFMA32(kf0, qf[ks], sacc0, 0, 0, 0);
            sacc1 = MFMA32(kf1, qf[ks], sacc1, 0, 0, 0);
        }

        // ---- lane-local online softmax over 64 kv (exp2 domain) ----
        const bool interior = (kv0g >= ctx + q0 - (WINDOW - QB)) &&
                              (kv0g + KVG - 1 <= ctx + q0);
        const int qpos = ctx + q0 + l31;
        float p2[2][16];
        float rmax = -INFINITY;
        #pragma unroll
        for (int m2 = 0; m2 < 2; ++m2) {
            #pragma unroll
            for (int r = 0; r < 16; ++r) {
                float x = (m2 == 0) ? sacc0[r] : sacc1[r];
                if (!interior) {
                    const int kpos = kv0g + m2 * 32 + (r & 3) + 4 * hi + 8 * (r >> 2);
                    const bool valid = (kpos <= qpos) && (qpos - kpos < WINDOW);
                    x = valid ? x : -INFINITY;
                }
                p2[m2][r] = x;
                rmax = fmaxf(rmax, x);
            }
        }
        rmax = fmaxf(rmax, __shfl_xor(rmax, 32));
        const float mold = mrun;
        const bool defer = __all(rmax <= mold + 11.0f);
        const float mnew = defer ? mold : fmaxf(mold, rmax);
        const float alpha = defer ? 1.0f
            : ((mold == -INFINITY) ? ((mnew == -INFINITY) ? 1.0f : 0.0f)
                                   : exp2f(mold - mnew));
        const bool dead = (mnew == -INFINITY);
        float rsum = 0.f;
        #pragma unroll
        for (int m2 = 0; m2 < 2; ++m2)
            #pragma unroll
            for (int r = 0; r < 16; ++r) {
                float e = dead ? 0.f : exp2f(p2[m2][r] - mnew);
                p2[m2][r] = e;
                rsum += e;
            }
        rsum += __shfl_xor(rsum, 32);
        lrun = lrun * alpha + rsum;
        mrun = mnew;
        if (!defer) {
            #pragma unroll
            for (int dblk = 0; dblk < 4; ++dblk)
                oacc[dblk] = oacc[dblk] * alpha;
        }

        // ---- pack P -> B-frags via shfl_xor(32) exchange ----
        short8 pb[2][2];
        #pragma unroll
        for (int m2 = 0; m2 < 2; ++m2) {
            unsigned int c0 = pack2bf(p2[m2][0],  p2[m2][1]);
            unsigned int c1 = pack2bf(p2[m2][2],  p2[m2][3]);
            unsigned int c2 = pack2bf(p2[m2][4],  p2[m2][5]);
            unsigned int c3 = pack2bf(p2[m2][6],  p2[m2][7]);
            unsigned int c4 = pack2bf(p2[m2][8],  p2[m2][9]);
            unsigned int c5 = pack2bf(p2[m2][10], p2[m2][11]);
            unsigned int c6 = pack2bf(p2[m2][12], p2[m2][13]);
            unsigned int c7 = pack2bf(p2[m2][14], p2[m2][15]);
            unsigned int o0 = (unsigned int)__shfl_xor((int)c0, 32);
            unsigned int o1 = (unsigned int)__shfl_xor((int)c1, 32);
            unsigned int o2 = (unsigned int)__shfl_xor((int)c2, 32);
            unsigned int o3 = (unsigned int)__shfl_xor((int)c3, 32);
            unsigned int o4 = (unsigned int)__shfl_xor((int)c4, 32);
            unsigned int o5 = (unsigned int)__shfl_xor((int)c5, 32);
            unsigned int o6 = (unsigned int)__shfl_xor((int)c6, 32);
            unsigned int o7 = (unsigned int)__shfl_xor((int)c7, 32);
            uint4v u0, u1;
            u0[0] = hi ? o2 : c0;
            u0[1] = hi ? o3 : c1;
            u0[2] = hi ? c2 : o0;
            u0[3] = hi ? c3 : o1;
            u1[0] = hi ? o6 : c4;
            u1[1] = hi ? o7 : c5;
            u1[2] = hi ? c6 : o4;
            u1[3] = hi ? c7 : o5;
            pb[m2][0] = __builtin_bit_cast(short8, u0);
            pb[m2][1] = __builtin_bit_cast(short8, u1);
        }

        // ---- PV 32x32: O^T += mfma32(A=V^T, B=P^T) ----
        #pragma unroll
        for (int m2 = 0; m2 < 2; ++m2) {
            #pragma unroll
            for (int dblk = 0; dblk < 4; ++dblk) {
                short8 vf0 = *(const short8*)&Vt[dblk * 32 + l31][kbase + m2 * 32 + hi * 8];
                short8 vf1 = *(const short8*)&Vt[dblk * 32 + l31][kbase + m2 * 32 + 16 + hi * 8];
                oacc[dblk] = MFMA32(vf0, pb[m2][0], oacc[dblk], 0, 0, 0);
                oacc[dblk] = MFMA32(vf1, pb[m2][1], oacc[dblk], 0, 0, 0);
            }
        }

        __syncthreads();   // bar2: all K/V reads done -> next iter store safe
    }
#undef LOAD_TILE
#undef LOAD_HALF

    // ---- combine: group B dumps (m,l,O) to LDS; group A merges + stores ----
    float* Od = (float*)smem;              // [4 heads][4 dblk][4 i4][64 lanes][4]
    float* ML = (float*)(smem + 65536);    // [4 heads][64 lanes][2]
    const int hd4 = wave & 3;
    if (hb == 1) {
        #pragma unroll
        for (int dblk = 0; dblk < 4; ++dblk)
            #pragma unroll
            for (int i4 = 0; i4 < 4; ++i4) {
                floatx4 o;
                o[0] = oacc[dblk][4 * i4 + 0];
                o[1] = oacc[dblk][4 * i4 + 1];
                o[2] = oacc[dblk][4 * i4 + 2];
                o[3] = oacc[dblk][4 * i4 + 3];
                *(floatx4*)&Od[hd4 * 4096 + dblk * 1024 + i4 * 256 + lane * 4] = o;
            }
        ML[hd4 * 128 + lane * 2]     = mrun;
        ML[hd4 * 128 + lane * 2 + 1] = lrun;
    }
    __syncthreads();
    if (hb == 0) {
        const float mB = ML[hd4 * 128 + lane * 2];
        const float lB = ML[hd4 * 128 + lane * 2 + 1];
        const float mT = fmaxf(mrun, mB);
        const float fA = (mrun == -INFINITY) ? 0.f : exp2f(mrun - mT);
        const float fB = (mB   == -INFINITY) ? 0.f : exp2f(mB - mT);
        const float inv = 1.0f / (lrun * fA + lB * fB);
        float* orow = outg + ((size_t)(qstart + q0 + l31) * HQN + hq) * HD;
        #pragma unroll
        for (int dblk = 0; dblk < 4; ++dblk) {
            #pragma unroll
            for (int rq = 0; rq < 4; ++rq) {
                floatx4 oB = *(const floatx4*)&Od[hd4 * 4096 + dblk * 1024 + rq * 256 + lane * 4];
                floatx4 o;
                o[0] = (oacc[dblk][4 * rq + 0] * fA + oB[0] * fB) * inv;
                o[1] = (oacc[dblk][4 * rq + 1] * fA + oB[1] * fB) * inv;
                o[2] = (oacc[dblk][4 * rq + 2] * fA + oB[2] * fB) * inv;
                o[3] = (oacc[dblk][4 * rq + 3] * fA + oB[3] * fB) * inv;
                *(floatx4*)(orow + dblk * 32 + 8 * rq + 4 * hi) = o;
            }
        }
    }
}

extern "C" void kernel_launch(void* const* d_in, const int* in_sizes, int n_in,
                              void* d_out, int out_size, void* d_ws, size_t ws_size,
                              hipStream_t stream) {
    const float* q  = (const float*)d_in[0];
    const float* k  = (const float*)d_in[1];
    const float* v  = (const float*)d_in[2];
    const int* btp  = (const int*)d_in[3];
    const int* sl   = (const int*)d_in[4];
    const int* qs   = (const int*)d_in[5];
    float* out      = (float*)d_out;

    static bool attr_set = false;
    if (!attr_set) {
        hipFuncSetAttribute((const void*)attn_fwd,
                            hipFuncAttributeMaxDynamicSharedMemorySize, 69632);
        attr_set = true;
    }
    attn_fwd<<<dim3(NSEQ * HKVN * 8), dim3(512), 69632, stream>>>(q, k, v, btp, sl, qs, out);
}

// Round 15
// 121.028 us; speedup vs baseline: 2.9203x; 2.9203x over previous
//
#include <hip/hip_runtime.h>
#include <stdint.h>

typedef __attribute__((ext_vector_type(8))) short short8;
typedef __attribute__((ext_vector_type(4))) float floatx4;
typedef __attribute__((ext_vector_type(16))) float f32x16;
typedef __attribute__((ext_vector_type(4))) unsigned int uint4v;

#define NSEQ 8
#define BLKSZ 16
#define NBLK_PER_SEQ 128
#define HQN 32
#define HKVN 8
#define GQ 4
#define HD 128
#define WINDOW 1024
// SCALE * log2(e): softmax in exp2 domain
#define QSCALE 0.12751744f

#define QB 32       // q rows per block
#define KVG 64      // kv per wave-group per iteration
#define KROW 136    // K lds row stride (bf16), [128][136]
#define VROW 136    // V^T lds col stride, [128][136]

#define MFMA32 __builtin_amdgcn_mfma_f32_32x32x16_bf16

// two f32 -> packed bf16x2 (round-half-up); low16 = lo, high16 = hi
static __device__ __forceinline__ unsigned int pack2bf(float lo, float hi) {
    unsigned int a = __builtin_bit_cast(unsigned int, lo) + 0x8000u;
    unsigned int b = __builtin_bit_cast(unsigned int, hi) + 0x8000u;
    return __builtin_amdgcn_perm(b, a, 0x07060302u);
}

extern __shared__ char smem[];   // 69632 B: K [128][136] | V^T [128][136]

__global__ __launch_bounds__(512, 2)
void attn_fwd(const float* __restrict__ qg,
              const float* __restrict__ kg,
              const float* __restrict__ vg,
              const int* __restrict__ bt,
              const int* __restrict__ seqlens,
              const int* __restrict__ qsl,
              float* __restrict__ outg)
{
    short (*Klds)[KROW] = (short(*)[KROW])smem;
    short (*Vt)[VROW]   = (short(*)[VROW])(smem + 34816);

    const int tid  = threadIdx.x;
    const int lane = tid & 63;
    const int wave = tid >> 6;        // 0..7
    const int hb   = tid >> 8;        // kv-split group 0/1
    const int t8   = tid & 255;      // index within half-block
    const int l31  = lane & 31;
    const int hi   = lane >> 5;

    // XCD pinning: b&7 = kv head
    const int b  = blockIdx.x;
    const int h  = b & 7;
    const int qt = (b >> 3) & 7;
    const int s  = b >> 6;
    const int q0 = qt * QB;

    const int qstart = qsl[s];
    const int numq   = qsl[s + 1] - qstart;
    const int slen   = seqlens[s];
    const int ctx    = slen - numq;
    const int hq     = h * GQ + (wave & 3);

    // ---- Q fragments (B-operand 32x32x16: col=q=l31, k=ks*16+hi*8+j), pre-scaled ----
    short8 qf[8];
    {
        const float* qrow = qg + ((size_t)(qstart + q0 + l31) * HQN + hq) * HD;
        #pragma unroll
        for (int ks = 0; ks < 8; ++ks) {
            floatx4 f0 = *(const floatx4*)(qrow + ks * 16 + hi * 8);
            floatx4 f1 = *(const floatx4*)(qrow + ks * 16 + hi * 8 + 4);
            uint4v w;
            w[0] = pack2bf(f0[0] * QSCALE, f0[1] * QSCALE);
            w[1] = pack2bf(f0[2] * QSCALE, f0[3] * QSCALE);
            w[2] = pack2bf(f1[0] * QSCALE, f1[1] * QSCALE);
            w[3] = pack2bf(f1[2] * QSCALE, f1[3] * QSCALE);
            qf[ks] = __builtin_bit_cast(short8, w);
        }
    }

    // O^T accumulators: lane q = l31, d = dblk*32 + (r&3) + 8*(r>>2) + 4*hi
    f32x16 oacc[4];
    #pragma unroll
    for (int dblk = 0; dblk < 4; ++dblk)
        #pragma unroll
        for (int i = 0; i < 16; ++i)
            oacc[dblk][i] = 0.f;

    float mrun = -INFINITY, lrun = 0.f;   // log2 units, per kv-group

    int lo = ctx + q0 - WINDOW + 1; if (lo < 0) lo = 0;
    int hiq = ctx + q0 + QB - 1;    if (hiq > slen - 1) hiq = slen - 1;
    const int t0 = lo >> 7, t1 = hiq >> 7;   // 128-kv block tiles

    // staging maps (within half-block; group stages its own kv-half)
    const int srow  = t8 >> 3;          // K: kv row 0..31 (+32 for p=1)
    const int sd0   = (t8 & 7) * 16;    // K: d offset (floats)
    const int k2    = t8 & 15;          // V: kv pair index
    const int d0v   = (t8 >> 4) * 8;    // V: d offset (0..120)
    const int kbase = hb * KVG;         // kv offset of this group

    floatx4 fk[8], fv[8];

#define LOAD_HALF(kv0_, p) {                                                         \
        const int kvp = (kv0_) + kbase + (p) * 32 + srow;                            \
        const int blk = bt[s * NBLK_PER_SEQ + (kvp >> 4)];                           \
        const float* src = kg + (((size_t)blk * BLKSZ + (kvp & 15)) * HKVN + h) * HD + sd0; \
        fk[(p)*4+0] = *(const floatx4*)(src);                                        \
        fk[(p)*4+1] = *(const floatx4*)(src + 4);                                    \
        fk[(p)*4+2] = *(const floatx4*)(src + 8);                                    \
        fk[(p)*4+3] = *(const floatx4*)(src + 12);                                   \
        const int kvv = (kv0_) + kbase + (p) * 32 + 2 * k2;                          \
        const int blkv = bt[s * NBLK_PER_SEQ + (kvv >> 4)];                          \
        const float* vsrc = vg + (((size_t)blkv * BLKSZ + (kvv & 15)) * HKVN + h) * HD + d0v; \
        fv[(p)*4+0] = *(const floatx4*)(vsrc);                                       \
        fv[(p)*4+1] = *(const floatx4*)(vsrc + 4);                                   \
        fv[(p)*4+2] = *(const floatx4*)(vsrc + (size_t)HKVN * HD);                   \
        fv[(p)*4+3] = *(const floatx4*)(vsrc + (size_t)HKVN * HD + 4);               \
    }
#define LOAD_TILE(kv0_) { LOAD_HALF(kv0_, 0); LOAD_HALF(kv0_, 1); }

    LOAD_TILE(t0 << 7);

    for (int t = t0; t <= t1; ++t) {
        const int kv0g = (t << 7) + kbase;   // this group's compute/staging base

        // ---- convert + store tile (each group stages its kv-half) ----
        #pragma unroll
        for (int p = 0; p < 2; ++p) {
            const int row = kbase + p * 32 + srow;
            uint4v w;
            w[0] = pack2bf(fk[p*4+0][0], fk[p*4+0][1]);
            w[1] = pack2bf(fk[p*4+0][2], fk[p*4+0][3]);
            w[2] = pack2bf(fk[p*4+1][0], fk[p*4+1][1]);
            w[3] = pack2bf(fk[p*4+1][2], fk[p*4+1][3]);
            *(uint4v*)&Klds[row][sd0] = w;
            w[0] = pack2bf(fk[p*4+2][0], fk[p*4+2][1]);
            w[1] = pack2bf(fk[p*4+2][2], fk[p*4+2][3]);
            w[2] = pack2bf(fk[p*4+3][0], fk[p*4+3][1]);
            w[3] = pack2bf(fk[p*4+3][2], fk[p*4+3][3]);
            *(uint4v*)&Klds[row][sd0 + 8] = w;
        }
        #pragma unroll
        for (int p = 0; p < 2; ++p)
            #pragma unroll
            for (int i = 0; i < 8; ++i) {
                *(unsigned int*)&Vt[d0v + i][kbase + p * 32 + 2 * k2] =
                    pack2bf(fv[p*4 + (i >> 2)][i & 3], fv[p*4 + 2 + (i >> 2)][i & 3]);
            }

        // ---- issue next tile's global loads ----
        if (t < t1) LOAD_TILE((t + 1) << 7);

        __syncthreads();   // bar1: staged tile visible

        // ---- swapped QK^T 32x32 on this group's two 32-kv halves ----
        f32x16 sacc0, sacc1;
        #pragma unroll
        for (int i = 0; i < 16; ++i) { sacc0[i] = 0.f; sacc1[i] = 0.f; }
        #pragma unroll
        for (int ks = 0; ks < 8; ++ks) {
            short8 kf0 = *(const short8*)&Klds[kbase + l31][ks * 16 + hi * 8];
            short8 kf1 = *(const short8*)&Klds[kbase + 32 + l31][ks * 16 + hi * 8];
            sacc0 = MFMA32(kf0, qf[ks], sacc0, 0, 0, 0);
            sacc1 = MFMA32(kf1, qf[ks], sacc1, 0, 0, 0);
        }

        // ---- lane-local online softmax over 64 kv (exp2 domain) ----
        const bool interior = (kv0g >= ctx + q0 - (WINDOW - QB)) &&
                              (kv0g + KVG - 1 <= ctx + q0);
        const int qpos = ctx + q0 + l31;
        float p2[2][16];
        float rmax = -INFINITY;
        #pragma unroll
        for (int m2 = 0; m2 < 2; ++m2) {
            #pragma unroll
            for (int r = 0; r < 16; ++r) {
                float x = (m2 == 0) ? sacc0[r] : sacc1[r];
                if (!interior) {
                    const int kpos = kv0g + m2 * 32 + (r & 3) + 4 * hi + 8 * (r >> 2);
                    const bool valid = (kpos <= qpos) && (qpos - kpos < WINDOW);
                    x = valid ? x : -INFINITY;
                }
                p2[m2][r] = x;
                rmax = fmaxf(rmax, x);
            }
        }
        rmax = fmaxf(rmax, __shfl_xor(rmax, 32));
        const float mold = mrun;
        const bool defer = __all(rmax <= mold + 11.0f);
        const float mnew = defer ? mold : fmaxf(mold, rmax);
        const float alpha = defer ? 1.0f
            : ((mold == -INFINITY) ? ((mnew == -INFINITY) ? 1.0f : 0.0f)
                                   : exp2f(mold - mnew));
        const bool dead = (mnew == -INFINITY);
        float rsum = 0.f;
        #pragma unroll
        for (int m2 = 0; m2 < 2; ++m2)
            #pragma unroll
            for (int r = 0; r < 16; ++r) {
                float e = dead ? 0.f : exp2f(p2[m2][r] - mnew);
                p2[m2][r] = e;
                rsum += e;
            }
        rsum += __shfl_xor(rsum, 32);
        lrun = lrun * alpha + rsum;
        mrun = mnew;
        if (!defer) {
            #pragma unroll
            for (int dblk = 0; dblk < 4; ++dblk)
                oacc[dblk] = oacc[dblk] * alpha;
        }

        // ---- pack P -> B-frags via shfl_xor(32) exchange ----
        short8 pb[2][2];
        #pragma unroll
        for (int m2 = 0; m2 < 2; ++m2) {
            unsigned int c0 = pack2bf(p2[m2][0],  p2[m2][1]);
            unsigned int c1 = pack2bf(p2[m2][2],  p2[m2][3]);
            unsigned int c2 = pack2bf(p2[m2][4],  p2[m2][5]);
            unsigned int c3 = pack2bf(p2[m2][6],  p2[m2][7]);
            unsigned int c4 = pack2bf(p2[m2][8],  p2[m2][9]);
            unsigned int c5 = pack2bf(p2[m2][10], p2[m2][11]);
            unsigned int c6 = pack2bf(p2[m2][12], p2[m2][13]);
            unsigned int c7 = pack2bf(p2[m2][14], p2[m2][15]);
            unsigned int o0 = (unsigned int)__shfl_xor((int)c0, 32);
            unsigned int o1 = (unsigned int)__shfl_xor((int)c1, 32);
            unsigned int o2 = (unsigned int)__shfl_xor((int)c2, 32);
            unsigned int o3 = (unsigned int)__shfl_xor((int)c3, 32);
            unsigned int o4 = (unsigned int)__shfl_xor((int)c4, 32);
            unsigned int o5 = (unsigned int)__shfl_xor((int)c5, 32);
            unsigned int o6 = (unsigned int)__shfl_xor((int)c6, 32);
            unsigned int o7 = (unsigned int)__shfl_xor((int)c7, 32);
            uint4v u0, u1;
            u0[0] = hi ? o2 : c0;
            u0[1] = hi ? o3 : c1;
            u0[2] = hi ? c2 : o0;
            u0[3] = hi ? c3 : o1;
            u1[0] = hi ? o6 : c4;
            u1[1] = hi ? o7 : c5;
            u1[2] = hi ? c6 : o4;
            u1[3] = hi ? c7 : o5;
            pb[m2][0] = __builtin_bit_cast(short8, u0);
            pb[m2][1] = __builtin_bit_cast(short8, u1);
        }

        // ---- PV 32x32: O^T += mfma32(A=V^T, B=P^T) ----
        #pragma unroll
        for (int m2 = 0; m2 < 2; ++m2) {
            #pragma unroll
            for (int dblk = 0; dblk < 4; ++dblk) {
                short8 vf0 = *(const short8*)&Vt[dblk * 32 + l31][kbase + m2 * 32 + hi * 8];
                short8 vf1 = *(const short8*)&Vt[dblk * 32 + l31][kbase + m2 * 32 + 16 + hi * 8];
                oacc[dblk] = MFMA32(vf0, pb[m2][0], oacc[dblk], 0, 0, 0);
                oacc[dblk] = MFMA32(vf1, pb[m2][1], oacc[dblk], 0, 0, 0);
            }
        }

        __syncthreads();   // bar2: all K/V reads done -> next iter store safe
    }
#undef LOAD_TILE
#undef LOAD_HALF

    // ---- combine: group B dumps (m,l,O) to LDS; group A merges + stores ----
    float* Od = (float*)smem;              // [4 heads][4 dblk][4 i4][64 lanes][4]
    float* ML = (float*)(smem + 65536);    // [4 heads][64 lanes][2]
    const int hd4 = wave & 3;
    if (hb == 1) {
        #pragma unroll
        for (int dblk = 0; dblk < 4; ++dblk)
            #pragma unroll
            for (int i4 = 0; i4 < 4; ++i4) {
                floatx4 o;
                o[0] = oacc[dblk][4 * i4 + 0];
                o[1] = oacc[dblk][4 * i4 + 1];
                o[2] = oacc[dblk][4 * i4 + 2];
                o[3] = oacc[dblk][4 * i4 + 3];
                *(floatx4*)&Od[hd4 * 4096 + dblk * 1024 + i4 * 256 + lane * 4] = o;
            }
        ML[hd4 * 128 + lane * 2]     = mrun;
        ML[hd4 * 128 + lane * 2 + 1] = lrun;
    }
    __syncthreads();
    if (hb == 0) {
        const float mB = ML[hd4 * 128 + lane * 2];
        const float lB = ML[hd4 * 128 + lane * 2 + 1];
        const float mT = fmaxf(mrun, mB);
        const float fA = (mrun == -INFINITY) ? 0.f : exp2f(mrun - mT);
        const float fB = (mB   == -INFINITY) ? 0.f : exp2f(mB - mT);
        const float inv = 1.0f / (lrun * fA + lB * fB);
        float* orow = outg + ((size_t)(qstart + q0 + l31) * HQN + hq) * HD;
        #pragma unroll
        for (int dblk = 0; dblk < 4; ++dblk) {
            #pragma unroll
            for (int rq = 0; rq < 4; ++rq) {
                floatx4 oB = *(const floatx4*)&Od[hd4 * 4096 + dblk * 1024 + rq * 256 + lane * 4];
                floatx4 o;
                o[0] = (oacc[dblk][4 * rq + 0] * fA + oB[0] * fB) * inv;
                o[1] = (oacc[dblk][4 * rq + 1] * fA + oB[1] * fB) * inv;
                o[2] = (oacc[dblk][4 * rq + 2] * fA + oB[2] * fB) * inv;
                o[3] = (oacc[dblk][4 * rq + 3] * fA + oB[3] * fB) * inv;
                *(floatx4*)(orow + dblk * 32 + 8 * rq + 4 * hi) = o;
            }
        }
    }
}

extern "C" void kernel_launch(void* const* d_in, const int* in_sizes, int n_in,
                              void* d_out, int out_size, void* d_ws, size_t ws_size,
                              hipStream_t stream) {
    const float* q  = (const float*)d_in[0];
    const float* k  = (const float*)d_in[1];
    const float* v  = (const float*)d_in[2];
    const int* btp  = (const int*)d_in[3];
    const int* sl   = (const int*)d_in[4];
    const int* qs   = (const int*)d_in[5];
    float* out      = (float*)d_out;

    hipFuncSetAttribute((const void*)attn_fwd,
                        hipFuncAttributeMaxDynamicSharedMemorySize, 69632);
    attn_fwd<<<dim3(NSEQ * HKVN * 8), dim3(512), 69632, stream>>>(q, k, v, btp, sl, qs, out);
}

// Round 17
// 83.609 us; speedup vs baseline: 4.2273x; 1.4476x over previous
//
#include <hip/hip_runtime.h>
#include <stdint.h>

typedef __attribute__((ext_vector_type(8))) short short8;
typedef __attribute__((ext_vector_type(4))) float floatx4;
typedef __attribute__((ext_vector_type(16))) float f32x16;
typedef __attribute__((ext_vector_type(4))) unsigned int uint4v;
typedef __attribute__((ext_vector_type(2))) unsigned int uint2v;

#define NSEQ 8
#define BLKSZ 16
#define NBLK_PER_SEQ 128
#define HQN 32
#define HKVN 8
#define GQ 4
#define HD 128
#define WINDOW 1024
// SCALE * log2(e): softmax in exp2 domain
#define QSCALE 0.12751744f

#define QB 32       // q rows per block (4 waves = 4 GQA heads share K/V)
#define KVB 64      // kv tile
#define KROW 136    // K lds row stride (bf16), single-buffered
#define VROW 72     // V^T lds row stride, double-buffered

#define MFMA32 __builtin_amdgcn_mfma_f32_32x32x16_bf16

// two f32 -> packed bf16x2 (round-half-up); low16 = lo, high16 = hi
static __device__ __forceinline__ unsigned int pack2bf(float lo, float hi) {
    unsigned int a = __builtin_bit_cast(unsigned int, lo) + 0x8000u;
    unsigned int b = __builtin_bit_cast(unsigned int, hi) + 0x8000u;
    return __builtin_amdgcn_perm(b, a, 0x07060302u);
}

// cross-half (lane ^ 32) reductions — proven __shfl_xor path
// (permlane32_swap builtin FAILED correctness in R16: semantics differ from
//  the modeled pair-delivery; do not reintroduce without a unit probe)
static __device__ __forceinline__ float xhalf_max(float x) {
    return fmaxf(x, __shfl_xor(x, 32));
}
static __device__ __forceinline__ float xhalf_sum(float x) {
    return x + __shfl_xor(x, 32);
}

__global__ __launch_bounds__(256, 2)
void attn_fwd(const float* __restrict__ qg,
              const float* __restrict__ kg,
              const float* __restrict__ vg,
              const int* __restrict__ bt,
              const int* __restrict__ seqlens,
              const int* __restrict__ qsl,
              float* __restrict__ outg)
{
    __shared__ __align__(16) short Klds[KVB][KROW];   // 17408 B (single)
    __shared__ __align__(16) short Vt[2][HD][VROW];   // 36864 B (dbuf) -> 54272 total

    const int tid  = threadIdx.x;
    const int lane = tid & 63;
    const int wave = tid >> 6;
    const int l31  = lane & 31;
    const int hi   = lane >> 5;

    // XCD pinning: consecutive block ids round-robin XCDs -> b&7 = kv head
    const int b  = blockIdx.x;
    const int h  = b & 7;
    const int qt = (b >> 3) & 7;
    const int s  = b >> 6;
    const int q0 = qt * QB;

    const int qstart = qsl[s];
    const int numq   = qsl[s + 1] - qstart;
    const int slen   = seqlens[s];
    const int ctx    = slen - numq;
    const int hq     = h * GQ + wave;

    // ---- Q fragments (B-operand 32x32x16: col=q=l31, k=ks*16+hi*8+j), pre-scaled ----
    short8 qf[8];
    {
        const float* qrow = qg + ((size_t)(qstart + q0 + l31) * HQN + hq) * HD;
        #pragma unroll
        for (int ks = 0; ks < 8; ++ks) {
            floatx4 f0 = *(const floatx4*)(qrow + ks * 16 + hi * 8);
            floatx4 f1 = *(const floatx4*)(qrow + ks * 16 + hi * 8 + 4);
            uint4v w;
            w[0] = pack2bf(f0[0] * QSCALE, f0[1] * QSCALE);
            w[1] = pack2bf(f0[2] * QSCALE, f0[3] * QSCALE);
            w[2] = pack2bf(f1[0] * QSCALE, f1[1] * QSCALE);
            w[3] = pack2bf(f1[2] * QSCALE, f1[3] * QSCALE);
            qf[ks] = __builtin_bit_cast(short8, w);
        }
    }

    // O^T accumulators: lane q = l31, d = dblk*32 + (r&3) + 8*(r>>2) + 4*hi
    f32x16 oacc[4];
    #pragma unroll
    for (int dblk = 0; dblk < 4; ++dblk)
        #pragma unroll
        for (int i = 0; i < 16; ++i)
            oacc[dblk][i] = 0.f;

    float mrun = -INFINITY, lrun = 0.f;   // log2 units

    int lo = ctx + q0 - WINDOW + 1; if (lo < 0) lo = 0;
    int hiq = ctx + q0 + QB - 1;    if (hiq > slen - 1) hiq = slen - 1;
    const int t0 = lo / KVB, t1 = hiq / KVB;

    // staging maps
    const int srow = tid >> 3;          // K: kv row 0..31 (+32 for p=1)
    const int sd0  = (tid & 7) * 16;    // K: d offset (floats)
    const int j4   = tid & 15;          // V: kv quad index (rows 4j4..4j4+3)
    const int d0v  = (tid >> 4) * 8;    // V: d offset (0..120)

    floatx4 fk[8], fv[8];               // raw f32 for next tile (T14 async split)

#define LOAD_K_HALF(kv0_, p) {                                                       \
        const int kvp = (kv0_) + (p) * 32 + srow;                                    \
        const int blk = bt[s * NBLK_PER_SEQ + (kvp >> 4)];                           \
        const float* src = kg + (((size_t)blk * BLKSZ + (kvp & 15)) * HKVN + h) * HD + sd0; \
        fk[(p)*4+0] = *(const floatx4*)(src);                                        \
        fk[(p)*4+1] = *(const floatx4*)(src + 4);                                    \
        fk[(p)*4+2] = *(const floatx4*)(src + 8);                                    \
        fk[(p)*4+3] = *(const floatx4*)(src + 12);                                   \
    }
#define LOAD_V(kv0_) {                                                               \
        const int kvv = (kv0_) + 4 * j4;                                             \
        const int blkv = bt[s * NBLK_PER_SEQ + (kvv >> 4)];                          \
        const float* vsrc = vg + (((size_t)blkv * BLKSZ + (kvv & 15)) * HKVN + h) * HD + d0v; \
        fv[0] = *(const floatx4*)(vsrc);                                             \
        fv[4] = *(const floatx4*)(vsrc + 4);                                         \
        fv[1] = *(const floatx4*)(vsrc + 1024);                                      \
        fv[5] = *(const floatx4*)(vsrc + 1028);                                      \
        fv[2] = *(const floatx4*)(vsrc + 2048);                                      \
        fv[6] = *(const floatx4*)(vsrc + 2052);                                      \
        fv[3] = *(const floatx4*)(vsrc + 3072);                                      \
        fv[7] = *(const floatx4*)(vsrc + 3076);                                      \
    }
#define LOAD_TILE(kv0_) { LOAD_K_HALF(kv0_, 0); LOAD_K_HALF(kv0_, 1); LOAD_V(kv0_); }

    LOAD_TILE(t0 * KVB);

    for (int t = t0; t <= t1; ++t) {
        const int kv0 = t * KVB;
        const int vb  = t & 1;

        // ---- convert + store tile t (K single, V dbuf; V via b64 quads) ----
        #pragma unroll
        for (int p = 0; p < 2; ++p) {
            const int row = p * 32 + srow;
            uint4v w;
            w[0] = pack2bf(fk[p*4+0][0], fk[p*4+0][1]);
            w[1] = pack2bf(fk[p*4+0][2], fk[p*4+0][3]);
            w[2] = pack2bf(fk[p*4+1][0], fk[p*4+1][1]);
            w[3] = pack2bf(fk[p*4+1][2], fk[p*4+1][3]);
            *(uint4v*)&Klds[row][sd0] = w;
            w[0] = pack2bf(fk[p*4+2][0], fk[p*4+2][1]);
            w[1] = pack2bf(fk[p*4+2][2], fk[p*4+2][3]);
            w[2] = pack2bf(fk[p*4+3][0], fk[p*4+3][1]);
            w[3] = pack2bf(fk[p*4+3][2], fk[p*4+3][3]);
            *(uint4v*)&Klds[row][sd0 + 8] = w;
        }
        #pragma unroll
        for (int d = 0; d < 8; ++d) {
            const float r0 = (d < 4) ? fv[0][d] : fv[4][d - 4];
            const float r1 = (d < 4) ? fv[1][d] : fv[5][d - 4];
            const float r2 = (d < 4) ? fv[2][d] : fv[6][d - 4];
            const float r3 = (d < 4) ? fv[3][d] : fv[7][d - 4];
            uint2v w;
            w[0] = pack2bf(r0, r1);   // kv 4j4, 4j4+1
            w[1] = pack2bf(r2, r3);   // kv 4j4+2, 4j4+3
            *(uint2v*)&Vt[vb][d0v + d][4 * j4] = w;
        }

        // ---- issue next tile's global loads ----
        if (t < t1) LOAD_TILE(kv0 + KVB);

        __syncthreads();   // barrier#1: staged tile visible

        // ---- swapped QK^T 32x32 on both kv-halves ----
        f32x16 sacc0, sacc1;
        #pragma unroll
        for (int i = 0; i < 16; ++i) { sacc0[i] = 0.f; sacc1[i] = 0.f; }
        #pragma unroll
        for (int ks = 0; ks < 8; ++ks) {
            short8 kf0 = *(const short8*)&Klds[l31][ks * 16 + hi * 8];
            short8 kf1 = *(const short8*)&Klds[32 + l31][ks * 16 + hi * 8];
            sacc0 = MFMA32(kf0, qf[ks], sacc0, 0, 0, 0);
            sacc1 = MFMA32(kf1, qf[ks], sacc1, 0, 0, 0);
        }

        __syncthreads();   // barrier#2: all K reads done -> next iter store safe

        // ---- lane-local online softmax over 64 kv (exp2 domain) ----
        const bool interior = (kv0 >= ctx + q0 - (WINDOW - QB)) &&
                              (kv0 + KVB - 1 <= ctx + q0);
        const int qpos = ctx + q0 + l31;
        float p2[2][16];
        float rmax = -INFINITY;
        #pragma unroll
        for (int m2 = 0; m2 < 2; ++m2) {
            #pragma unroll
            for (int r = 0; r < 16; ++r) {
                float x = (m2 == 0) ? sacc0[r] : sacc1[r];
                if (!interior) {
                    const int kpos = kv0 + m2 * 32 + (r & 3) + 4 * hi + 8 * (r >> 2);
                    const bool valid = (kpos <= qpos) && (qpos - kpos < WINDOW);
                    x = valid ? x : -INFINITY;
                }
                p2[m2][r] = x;
                rmax = fmaxf(rmax, x);
            }
        }
        rmax = xhalf_max(rmax);
        const float mold = mrun;
        const bool defer = __all(rmax <= mold + 11.0f);   // THR ~ 8 nats in log2
        const float mnew = defer ? mold : fmaxf(mold, rmax);
        const float alpha = defer ? 1.0f
            : ((mold == -INFINITY) ? ((mnew == -INFINITY) ? 1.0f : 0.0f)
                                   : exp2f(mold - mnew));
        const bool dead = (mnew == -INFINITY);
        float rsum = 0.f;
        #pragma unroll
        for (int m2 = 0; m2 < 2; ++m2)
            #pragma unroll
            for (int r = 0; r < 16; ++r) {
                float e = dead ? 0.f : exp2f(p2[m2][r] - mnew);
                p2[m2][r] = e;
                rsum += e;
            }
        rsum = xhalf_sum(rsum);
        lrun = lrun * alpha + rsum;
        mrun = mnew;
        if (!defer) {
            #pragma unroll
            for (int dblk = 0; dblk < 4; ++dblk)
                oacc[dblk] = oacc[dblk] * alpha;
        }

        // ---- pack P -> B-frags; pre-selected single-shfl cross-half exchange ----
        // hi=0 needs partner's {c0,c1,c4,c5}; hi=1 needs partner's {c2,c3,c6,c7}.
        // Each lane sends the complementary set: s = hi ? {c0,c1,c4,c5} : {c2,c3,c6,c7}.
        short8 pb[2][2];
        #pragma unroll
        for (int m2 = 0; m2 < 2; ++m2) {
            unsigned int c0 = pack2bf(p2[m2][0],  p2[m2][1]);
            unsigned int c1 = pack2bf(p2[m2][2],  p2[m2][3]);
            unsigned int c2 = pack2bf(p2[m2][4],  p2[m2][5]);
            unsigned int c3 = pack2bf(p2[m2][6],  p2[m2][7]);
            unsigned int c4 = pack2bf(p2[m2][8],  p2[m2][9]);
            unsigned int c5 = pack2bf(p2[m2][10], p2[m2][11]);
            unsigned int c6 = pack2bf(p2[m2][12], p2[m2][13]);
            unsigned int c7 = pack2bf(p2[m2][14], p2[m2][15]);
            unsigned int s0 = hi ? c0 : c2;
            unsigned int s1 = hi ? c1 : c3;
            unsigned int s2 = hi ? c4 : c6;
            unsigned int s3 = hi ? c5 : c7;
            unsigned int r0 = (unsigned int)__shfl_xor((int)s0, 32);
            unsigned int r1 = (unsigned int)__shfl_xor((int)s1, 32);
            unsigned int r2 = (unsigned int)__shfl_xor((int)s2, 32);
            unsigned int r3 = (unsigned int)__shfl_xor((int)s3, 32);
            uint4v u0, u1;
            u0[0] = hi ? r0 : c0;
            u0[1] = hi ? r1 : c1;
            u0[2] = hi ? c2 : r0;
            u0[3] = hi ? c3 : r1;
            u1[0] = hi ? r2 : c4;
            u1[1] = hi ? r3 : c5;
            u1[2] = hi ? c6 : r2;
            u1[3] = hi ? c7 : r3;
            pb[m2][0] = __builtin_bit_cast(short8, u0);   // kv m2*32 + 0..15
            pb[m2][1] = __builtin_bit_cast(short8, u1);   // kv m2*32 + 16..31
        }

        // ---- PV 32x32: O^T += mfma32(A=V^T, B=P^T), both kv-halves ----
        #pragma unroll
        for (int m2 = 0; m2 < 2; ++m2) {
            #pragma unroll
            for (int dblk = 0; dblk < 4; ++dblk) {
                short8 vf0 = *(const short8*)&Vt[vb][dblk * 32 + l31][m2 * 32 + hi * 8];
                short8 vf1 = *(const short8*)&Vt[vb][dblk * 32 + l31][m2 * 32 + 16 + hi * 8];
                oacc[dblk] = MFMA32(vf0, pb[m2][0], oacc[dblk], 0, 0, 0);
                oacc[dblk] = MFMA32(vf1, pb[m2][1], oacc[dblk], 0, 0, 0);
            }
        }
    }
#undef LOAD_TILE
#undef LOAD_V
#undef LOAD_K_HALF

    // ---- epilogue: lane-local normalize, b128 stores ----
    {
        const float inv = 1.0f / lrun;
        float* orow = outg + ((size_t)(qstart + q0 + l31) * HQN + hq) * HD;
        #pragma unroll
        for (int dblk = 0; dblk < 4; ++dblk) {
            #pragma unroll
            for (int rq = 0; rq < 4; ++rq) {
                floatx4 o;
                o[0] = oacc[dblk][4 * rq + 0] * inv;
                o[1] = oacc[dblk][4 * rq + 1] * inv;
                o[2] = oacc[dblk][4 * rq + 2] * inv;
                o[3] = oacc[dblk][4 * rq + 3] * inv;
                *(floatx4*)(orow + dblk * 32 + 8 * rq + 4 * hi) = o;
            }
        }
    }
}

extern "C" void kernel_launch(void* const* d_in, const int* in_sizes, int n_in,
                              void* d_out, int out_size, void* d_ws, size_t ws_size,
                              hipStream_t stream) {
    const float* q  = (const float*)d_in[0];
    const float* k  = (const float*)d_in[1];
    const float* v  = (const float*)d_in[2];
    const int* btp  = (const int*)d_in[3];
    const int* sl   = (const int*)d_in[4];
    const int* qs   = (const int*)d_in[5];
    float* out      = (float*)d_out;

    attn_fwd<<<dim3(NSEQ * HKVN * 8), 256, 0, stream>>>(q, k, v, btp, sl, qs, out);
}

// Round 18
// 81.426 us; speedup vs baseline: 4.3405x; 1.0268x over previous
//
#include <hip/hip_runtime.h>
#include <stdint.h>

typedef __attribute__((ext_vector_type(8))) short short8;
typedef __attribute__((ext_vector_type(4))) float floatx4;
typedef __attribute__((ext_vector_type(16))) float f32x16;
typedef __attribute__((ext_vector_type(4))) unsigned int uint4v;
typedef __attribute__((ext_vector_type(2))) unsigned int uint2v;

#define NSEQ 8
#define BLKSZ 16
#define NBLK_PER_SEQ 128
#define HQN 32
#define HKVN 8
#define GQ 4
#define HD 128
#define WINDOW 1024
// SCALE * log2(e): softmax in exp2 domain
#define QSCALE 0.12751744f

#define QB 32       // q rows per block (4 waves = 4 GQA heads share K/V)
#define KVB 64      // kv tile
#define KROW 136    // K lds row stride (bf16), single-buffered
#define VROW 72     // V^T lds row stride, double-buffered

#define MFMA32 __builtin_amdgcn_mfma_f32_32x32x16_bf16

// two f32 -> packed bf16x2 (round-half-up); low16 = lo, high16 = hi
static __device__ __forceinline__ unsigned int pack2bf(float lo, float hi) {
    unsigned int a = __builtin_bit_cast(unsigned int, lo) + 0x8000u;
    unsigned int b = __builtin_bit_cast(unsigned int, hi) + 0x8000u;
    return __builtin_amdgcn_perm(b, a, 0x07060302u);
}

// cross-half (lane ^ 32) reductions — proven __shfl_xor path
static __device__ __forceinline__ float xhalf_max(float x) {
    return fmaxf(x, __shfl_xor(x, 32));
}
static __device__ __forceinline__ float xhalf_sum(float x) {
    return x + __shfl_xor(x, 32);
}

__global__ __launch_bounds__(256, 2)
void attn_fwd(const float* __restrict__ qg,
              const float* __restrict__ kg,
              const float* __restrict__ vg,
              const int* __restrict__ bt,
              const int* __restrict__ seqlens,
              const int* __restrict__ qsl,
              float* __restrict__ outg)
{
    __shared__ __align__(16) short Klds[KVB][KROW];   // 17408 B (single)
    __shared__ __align__(16) short Vt[2][HD][VROW];   // 36864 B (dbuf) -> 54272 total

    const int tid  = threadIdx.x;
    const int lane = tid & 63;
    const int wave = tid >> 6;
    const int l31  = lane & 31;
    const int hi   = lane >> 5;

    // XCD pinning: consecutive block ids round-robin XCDs -> b&7 = kv head
    const int b  = blockIdx.x;
    const int h  = b & 7;
    const int qt = (b >> 3) & 7;
    const int s  = b >> 6;
    const int q0 = qt * QB;

    const int qstart = qsl[s];
    const int numq   = qsl[s + 1] - qstart;
    const int slen   = seqlens[s];
    const int ctx    = slen - numq;
    const int hq     = h * GQ + wave;

    // ---- Q fragments (B-operand 32x32x16: col=q=l31, k=ks*16+hi*8+j), pre-scaled ----
    short8 qf[8];
    {
        const float* qrow = qg + ((size_t)(qstart + q0 + l31) * HQN + hq) * HD;
        #pragma unroll
        for (int ks = 0; ks < 8; ++ks) {
            floatx4 f0 = *(const floatx4*)(qrow + ks * 16 + hi * 8);
            floatx4 f1 = *(const floatx4*)(qrow + ks * 16 + hi * 8 + 4);
            uint4v w;
            w[0] = pack2bf(f0[0] * QSCALE, f0[1] * QSCALE);
            w[1] = pack2bf(f0[2] * QSCALE, f0[3] * QSCALE);
            w[2] = pack2bf(f1[0] * QSCALE, f1[1] * QSCALE);
            w[3] = pack2bf(f1[2] * QSCALE, f1[3] * QSCALE);
            qf[ks] = __builtin_bit_cast(short8, w);
        }
    }

    // O^T accumulators: lane q = l31, d = dblk*32 + (r&3) + 8*(r>>2) + 4*hi
    f32x16 oacc[4];
    #pragma unroll
    for (int dblk = 0; dblk < 4; ++dblk)
        #pragma unroll
        for (int i = 0; i < 16; ++i)
            oacc[dblk][i] = 0.f;

    float mrun = -INFINITY, lrun = 0.f;   // log2 units

    int lo = ctx + q0 - WINDOW + 1; if (lo < 0) lo = 0;
    int hiq = ctx + q0 + QB - 1;    if (hiq > slen - 1) hiq = slen - 1;
    const int t0 = lo / KVB, t1 = hiq / KVB;

    // staging maps
    const int srow = tid >> 3;          // K: kv row 0..31 (+32 for p=1)
    const int sd0  = (tid & 7) * 16;    // K: d offset (floats)
    const int j4   = tid & 15;          // V: kv quad index (rows 4j4..4j4+3)
    const int d0v  = (tid >> 4) * 8;    // V: d offset (0..120)

    floatx4 fk[8], fv[8];               // raw f32 for next tile

#define LOAD_K_HALF(kv0_, p) {                                                       \
        const int kvp = (kv0_) + (p) * 32 + srow;                                    \
        const int blk = bt[s * NBLK_PER_SEQ + (kvp >> 4)];                           \
        const float* src = kg + (((size_t)blk * BLKSZ + (kvp & 15)) * HKVN + h) * HD + sd0; \
        fk[(p)*4+0] = *(const floatx4*)(src);                                        \
        fk[(p)*4+1] = *(const floatx4*)(src + 4);                                    \
        fk[(p)*4+2] = *(const floatx4*)(src + 8);                                    \
        fk[(p)*4+3] = *(const floatx4*)(src + 12);                                   \
    }
#define LOAD_V(kv0_) {                                                               \
        const int kvv = (kv0_) + 4 * j4;                                             \
        const int blkv = bt[s * NBLK_PER_SEQ + (kvv >> 4)];                          \
        const float* vsrc = vg + (((size_t)blkv * BLKSZ + (kvv & 15)) * HKVN + h) * HD + d0v; \
        fv[0] = *(const floatx4*)(vsrc);                                             \
        fv[4] = *(const floatx4*)(vsrc + 4);                                         \
        fv[1] = *(const floatx4*)(vsrc + 1024);                                      \
        fv[5] = *(const floatx4*)(vsrc + 1028);                                      \
        fv[2] = *(const floatx4*)(vsrc + 2048);                                      \
        fv[6] = *(const floatx4*)(vsrc + 2052);                                      \
        fv[3] = *(const floatx4*)(vsrc + 3072);                                      \
        fv[7] = *(const floatx4*)(vsrc + 3076);                                      \
    }
#define LOAD_TILE(kv0_) { LOAD_K_HALF(kv0_, 0); LOAD_K_HALF(kv0_, 1); LOAD_V(kv0_); }

    LOAD_TILE(t0 * KVB);

    for (int t = t0; t <= t1; ++t) {
        const int kv0 = t * KVB;
        const int vb  = t & 1;

        // ---- convert + store tile t (K single, V dbuf; V via b64 quads) ----
        // (consumes fk/fv: the compiler-inserted vmcnt waits land HERE, with no
        //  intervening barrier since issue -> loads truly overlap prior compute)
        #pragma unroll
        for (int p = 0; p < 2; ++p) {
            const int row = p * 32 + srow;
            uint4v w;
            w[0] = pack2bf(fk[p*4+0][0], fk[p*4+0][1]);
            w[1] = pack2bf(fk[p*4+0][2], fk[p*4+0][3]);
            w[2] = pack2bf(fk[p*4+1][0], fk[p*4+1][1]);
            w[3] = pack2bf(fk[p*4+1][2], fk[p*4+1][3]);
            *(uint4v*)&Klds[row][sd0] = w;
            w[0] = pack2bf(fk[p*4+2][0], fk[p*4+2][1]);
            w[1] = pack2bf(fk[p*4+2][2], fk[p*4+2][3]);
            w[2] = pack2bf(fk[p*4+3][0], fk[p*4+3][1]);
            w[3] = pack2bf(fk[p*4+3][2], fk[p*4+3][3]);
            *(uint4v*)&Klds[row][sd0 + 8] = w;
        }
        #pragma unroll
        for (int d = 0; d < 8; ++d) {
            const float r0 = (d < 4) ? fv[0][d] : fv[4][d - 4];
            const float r1 = (d < 4) ? fv[1][d] : fv[5][d - 4];
            const float r2 = (d < 4) ? fv[2][d] : fv[6][d - 4];
            const float r3 = (d < 4) ? fv[3][d] : fv[7][d - 4];
            uint2v w;
            w[0] = pack2bf(r0, r1);   // kv 4j4, 4j4+1
            w[1] = pack2bf(r2, r3);   // kv 4j4+2, 4j4+3
            *(uint2v*)&Vt[vb][d0v + d][4 * j4] = w;
        }

        __syncthreads();   // barrier#1: staged tile visible (vmcnt already 0 here)

        // ---- swapped QK^T 32x32 on both kv-halves ----
        f32x16 sacc0, sacc1;
        #pragma unroll
        for (int i = 0; i < 16; ++i) { sacc0[i] = 0.f; sacc1[i] = 0.f; }
        #pragma unroll
        for (int ks = 0; ks < 8; ++ks) {
            short8 kf0 = *(const short8*)&Klds[l31][ks * 16 + hi * 8];
            short8 kf1 = *(const short8*)&Klds[32 + l31][ks * 16 + hi * 8];
            sacc0 = MFMA32(kf0, qf[ks], sacc0, 0, 0, 0);
            sacc1 = MFMA32(kf1, qf[ks], sacc1, 0, 0, 0);
        }

        __syncthreads();   // barrier#2: all K reads done -> next iter store safe

        // ---- issue next tile's loads NOW: in flight across softmax+PV, no
        //      barrier crosses them before consumption at next loop top ----
        if (t < t1) LOAD_TILE(kv0 + KVB);

        // ---- lane-local online softmax over 64 kv (exp2 domain) ----
        const bool interior = (kv0 >= ctx + q0 - (WINDOW - QB)) &&
                              (kv0 + KVB - 1 <= ctx + q0);
        const int qpos = ctx + q0 + l31;
        float p2[2][16];
        float rmax = -INFINITY;
        #pragma unroll
        for (int m2 = 0; m2 < 2; ++m2) {
            #pragma unroll
            for (int r = 0; r < 16; ++r) {
                float x = (m2 == 0) ? sacc0[r] : sacc1[r];
                if (!interior) {
                    const int kpos = kv0 + m2 * 32 + (r & 3) + 4 * hi + 8 * (r >> 2);
                    const bool valid = (kpos <= qpos) && (qpos - kpos < WINDOW);
                    x = valid ? x : -INFINITY;
                }
                p2[m2][r] = x;
                rmax = fmaxf(rmax, x);
            }
        }
        rmax = xhalf_max(rmax);
        const float mold = mrun;
        const bool defer = __all(rmax <= mold + 11.0f);   // THR ~ 8 nats in log2
        const float mnew = defer ? mold : fmaxf(mold, rmax);
        const float alpha = defer ? 1.0f
            : ((mold == -INFINITY) ? ((mnew == -INFINITY) ? 1.0f : 0.0f)
                                   : exp2f(mold - mnew));
        const bool dead = (mnew == -INFINITY);
        float rsum = 0.f;
        #pragma unroll
        for (int m2 = 0; m2 < 2; ++m2)
            #pragma unroll
            for (int r = 0; r < 16; ++r) {
                float e = dead ? 0.f : exp2f(p2[m2][r] - mnew);
                p2[m2][r] = e;
                rsum += e;
            }
        rsum = xhalf_sum(rsum);
        lrun = lrun * alpha + rsum;
        mrun = mnew;
        if (!defer) {
            #pragma unroll
            for (int dblk = 0; dblk < 4; ++dblk)
                oacc[dblk] = oacc[dblk] * alpha;
        }

        // ---- pack P -> B-frags; pre-selected single-shfl cross-half exchange ----
        short8 pb[2][2];
        #pragma unroll
        for (int m2 = 0; m2 < 2; ++m2) {
            unsigned int c0 = pack2bf(p2[m2][0],  p2[m2][1]);
            unsigned int c1 = pack2bf(p2[m2][2],  p2[m2][3]);
            unsigned int c2 = pack2bf(p2[m2][4],  p2[m2][5]);
            unsigned int c3 = pack2bf(p2[m2][6],  p2[m2][7]);
            unsigned int c4 = pack2bf(p2[m2][8],  p2[m2][9]);
            unsigned int c5 = pack2bf(p2[m2][10], p2[m2][11]);
            unsigned int c6 = pack2bf(p2[m2][12], p2[m2][13]);
            unsigned int c7 = pack2bf(p2[m2][14], p2[m2][15]);
            unsigned int s0 = hi ? c0 : c2;
            unsigned int s1 = hi ? c1 : c3;
            unsigned int s2 = hi ? c4 : c6;
            unsigned int s3 = hi ? c5 : c7;
            unsigned int r0 = (unsigned int)__shfl_xor((int)s0, 32);
            unsigned int r1 = (unsigned int)__shfl_xor((int)s1, 32);
            unsigned int r2 = (unsigned int)__shfl_xor((int)s2, 32);
            unsigned int r3 = (unsigned int)__shfl_xor((int)s3, 32);
            uint4v u0, u1;
            u0[0] = hi ? r0 : c0;
            u0[1] = hi ? r1 : c1;
            u0[2] = hi ? c2 : r0;
            u0[3] = hi ? c3 : r1;
            u1[0] = hi ? r2 : c4;
            u1[1] = hi ? r3 : c5;
            u1[2] = hi ? c6 : r2;
            u1[3] = hi ? c7 : r3;
            pb[m2][0] = __builtin_bit_cast(short8, u0);   // kv m2*32 + 0..15
            pb[m2][1] = __builtin_bit_cast(short8, u1);   // kv m2*32 + 16..31
        }

        // ---- PV 32x32: O^T += mfma32(A=V^T, B=P^T), both kv-halves ----
        #pragma unroll
        for (int m2 = 0; m2 < 2; ++m2) {
            #pragma unroll
            for (int dblk = 0; dblk < 4; ++dblk) {
                short8 vf0 = *(const short8*)&Vt[vb][dblk * 32 + l31][m2 * 32 + hi * 8];
                short8 vf1 = *(const short8*)&Vt[vb][dblk * 32 + l31][m2 * 32 + 16 + hi * 8];
                oacc[dblk] = MFMA32(vf0, pb[m2][0], oacc[dblk], 0, 0, 0);
                oacc[dblk] = MFMA32(vf1, pb[m2][1], oacc[dblk], 0, 0, 0);
            }
        }
    }
#undef LOAD_TILE
#undef LOAD_V
#undef LOAD_K_HALF

    // ---- epilogue: lane-local normalize, b128 stores ----
    {
        const float inv = 1.0f / lrun;
        float* orow = outg + ((size_t)(qstart + q0 + l31) * HQN + hq) * HD;
        #pragma unroll
        for (int dblk = 0; dblk < 4; ++dblk) {
            #pragma unroll
            for (int rq = 0; rq < 4; ++rq) {
                floatx4 o;
                o[0] = oacc[dblk][4 * rq + 0] * inv;
                o[1] = oacc[dblk][4 * rq + 1] * inv;
                o[2] = oacc[dblk][4 * rq + 2] * inv;
                o[3] = oacc[dblk][4 * rq + 3] * inv;
                *(floatx4*)(orow + dblk * 32 + 8 * rq + 4 * hi) = o;
            }
        }
    }
}

extern "C" void kernel_launch(void* const* d_in, const int* in_sizes, int n_in,
                              void* d_out, int out_size, void* d_ws, size_t ws_size,
                              hipStream_t stream) {
    const float* q  = (const float*)d_in[0];
    const float* k  = (const float*)d_in[1];
    const float* v  = (const float*)d_in[2];
    const int* btp  = (const int*)d_in[3];
    const int* sl   = (const int*)d_in[4];
    const int* qs   = (const int*)d_in[5];
    float* out      = (float*)d_out;

    attn_fwd<<<dim3(NSEQ * HKVN * 8), 256, 0, stream>>>(q, k, v, btp, sl, qs, out);
}

// Round 19
// 77.767 us; speedup vs baseline: 4.5448x; 1.0471x over previous
//
#include <hip/hip_runtime.h>
#include <stdint.h>

typedef __attribute__((ext_vector_type(8))) short short8;
typedef __attribute__((ext_vector_type(4))) float floatx4;
typedef __attribute__((ext_vector_type(16))) float f32x16;
typedef __attribute__((ext_vector_type(4))) unsigned int uint4v;
typedef __attribute__((ext_vector_type(2))) unsigned int uint2v;

#define NSEQ 8
#define BLKSZ 16
#define NBLK_PER_SEQ 128
#define HQN 32
#define HKVN 8
#define GQ 4
#define HD 128
#define WINDOW 1024
// SCALE * log2(e): softmax in exp2 domain
#define QSCALE 0.12751744f

#define QB 32       // q rows per block (4 waves = 4 GQA heads share K/V)
#define KVB 64      // kv tile
#define KROW 136    // K lds row stride (bf16), single-buffered
#define VROW 72     // V^T lds row stride, double-buffered

#define MFMA32 __builtin_amdgcn_mfma_f32_32x32x16_bf16

// two f32 -> packed bf16x2 (round-half-up); low16 = lo, high16 = hi
static __device__ __forceinline__ unsigned int pack2bf(float lo, float hi) {
    unsigned int a = __builtin_bit_cast(unsigned int, lo) + 0x8000u;
    unsigned int b = __builtin_bit_cast(unsigned int, hi) + 0x8000u;
    return __builtin_amdgcn_perm(b, a, 0x07060302u);
}

// cross-half (lane ^ 32) max — proven __shfl_xor path
static __device__ __forceinline__ float xhalf_max(float x) {
    return fmaxf(x, __shfl_xor(x, 32));
}

__global__ __launch_bounds__(256, 2)
void attn_fwd(const float* __restrict__ qg,
              const float* __restrict__ kg,
              const float* __restrict__ vg,
              const int* __restrict__ bt,
              const int* __restrict__ seqlens,
              const int* __restrict__ qsl,
              float* __restrict__ outg)
{
    __shared__ __align__(16) short Klds[KVB][KROW];   // 17408 B (single)
    __shared__ __align__(16) short Vt[2][HD][VROW];   // 36864 B (dbuf) -> 54272 total

    const int tid  = threadIdx.x;
    const int lane = tid & 63;
    const int wave = tid >> 6;
    const int l31  = lane & 31;
    const int hi   = lane >> 5;

    // XCD pinning: consecutive block ids round-robin XCDs -> b&7 = kv head
    const int b  = blockIdx.x;
    const int h  = b & 7;
    const int qt = (b >> 3) & 7;
    const int s  = b >> 6;
    const int q0 = qt * QB;

    const int qstart = qsl[s];
    const int numq   = qsl[s + 1] - qstart;
    const int slen   = seqlens[s];
    const int ctx    = slen - numq;
    const int hq     = h * GQ + wave;

    // ---- Q fragments (B-operand 32x32x16: col=q=l31, k=ks*16+hi*8+j), pre-scaled ----
    short8 qf[8];
    {
        const float* qrow = qg + ((size_t)(qstart + q0 + l31) * HQN + hq) * HD;
        #pragma unroll
        for (int ks = 0; ks < 8; ++ks) {
            floatx4 f0 = *(const floatx4*)(qrow + ks * 16 + hi * 8);
            floatx4 f1 = *(const floatx4*)(qrow + ks * 16 + hi * 8 + 4);
            uint4v w;
            w[0] = pack2bf(f0[0] * QSCALE, f0[1] * QSCALE);
            w[1] = pack2bf(f0[2] * QSCALE, f0[3] * QSCALE);
            w[2] = pack2bf(f1[0] * QSCALE, f1[1] * QSCALE);
            w[3] = pack2bf(f1[2] * QSCALE, f1[3] * QSCALE);
            qf[ks] = __builtin_bit_cast(short8, w);
        }
    }

    // O^T accumulators: lane q = l31, d = dblk*32 + (r&3) + 8*(r>>2) + 4*hi
    f32x16 oacc[4];
    #pragma unroll
    for (int dblk = 0; dblk < 4; ++dblk)
        #pragma unroll
        for (int i = 0; i < 16; ++i)
            oacc[dblk][i] = 0.f;

    float mrun = -INFINITY;   // log2 units, shared across halves
    float lrun = 0.f;         // PER-HALF partial sum; merged once in epilogue

    int lo = ctx + q0 - WINDOW + 1; if (lo < 0) lo = 0;
    int hiq = ctx + q0 + QB - 1;    if (hiq > slen - 1) hiq = slen - 1;
    const int t0 = lo / KVB, t1 = hiq / KVB;

    // staging maps
    const int srow = tid >> 3;          // K: kv row 0..31 (+32 for p=1)
    const int sd0  = (tid & 7) * 16;    // K: d offset (floats)
    const int j4   = tid & 15;          // V: kv quad index (rows 4j4..4j4+3)
    const int d0v  = (tid >> 4) * 8;    // V: d offset (0..120)

    floatx4 fk[8], fv[8];               // raw f32 for next tile

#define LOAD_K_HALF(kv0_, p) {                                                       \
        const int kvp = (kv0_) + (p) * 32 + srow;                                    \
        const int blk = bt[s * NBLK_PER_SEQ + (kvp >> 4)];                           \
        const float* src = kg + (((size_t)blk * BLKSZ + (kvp & 15)) * HKVN + h) * HD + sd0; \
        fk[(p)*4+0] = *(const floatx4*)(src);                                        \
        fk[(p)*4+1] = *(const floatx4*)(src + 4);                                    \
        fk[(p)*4+2] = *(const floatx4*)(src + 8);                                    \
        fk[(p)*4+3] = *(const floatx4*)(src + 12);                                   \
    }
#define LOAD_V(kv0_) {                                                               \
        const int kvv = (kv0_) + 4 * j4;                                             \
        const int blkv = bt[s * NBLK_PER_SEQ + (kvv >> 4)];                          \
        const float* vsrc = vg + (((size_t)blkv * BLKSZ + (kvv & 15)) * HKVN + h) * HD + d0v; \
        fv[0] = *(const floatx4*)(vsrc);                                             \
        fv[4] = *(const floatx4*)(vsrc + 4);                                         \
        fv[1] = *(const floatx4*)(vsrc + 1024);                                      \
        fv[5] = *(const floatx4*)(vsrc + 1028);                                      \
        fv[2] = *(const floatx4*)(vsrc + 2048);                                      \
        fv[6] = *(const floatx4*)(vsrc + 2052);                                      \
        fv[3] = *(const floatx4*)(vsrc + 3072);                                      \
        fv[7] = *(const floatx4*)(vsrc + 3076);                                      \
    }
#define LOAD_TILE(kv0_) { LOAD_K_HALF(kv0_, 0); LOAD_K_HALF(kv0_, 1); LOAD_V(kv0_); }

    LOAD_TILE(t0 * KVB);

    for (int t = t0; t <= t1; ++t) {
        const int kv0 = t * KVB;
        const int vb  = t & 1;

        // ---- convert + store tile t (K single, V dbuf; V via b64 quads) ----
        #pragma unroll
        for (int p = 0; p < 2; ++p) {
            const int row = p * 32 + srow;
            uint4v w;
            w[0] = pack2bf(fk[p*4+0][0], fk[p*4+0][1]);
            w[1] = pack2bf(fk[p*4+0][2], fk[p*4+0][3]);
            w[2] = pack2bf(fk[p*4+1][0], fk[p*4+1][1]);
            w[3] = pack2bf(fk[p*4+1][2], fk[p*4+1][3]);
            *(uint4v*)&Klds[row][sd0] = w;
            w[0] = pack2bf(fk[p*4+2][0], fk[p*4+2][1]);
            w[1] = pack2bf(fk[p*4+2][2], fk[p*4+2][3]);
            w[2] = pack2bf(fk[p*4+3][0], fk[p*4+3][1]);
            w[3] = pack2bf(fk[p*4+3][2], fk[p*4+3][3]);
            *(uint4v*)&Klds[row][sd0 + 8] = w;
        }
        #pragma unroll
        for (int d = 0; d < 8; ++d) {
            const float r0 = (d < 4) ? fv[0][d] : fv[4][d - 4];
            const float r1 = (d < 4) ? fv[1][d] : fv[5][d - 4];
            const float r2 = (d < 4) ? fv[2][d] : fv[6][d - 4];
            const float r3 = (d < 4) ? fv[3][d] : fv[7][d - 4];
            uint2v w;
            w[0] = pack2bf(r0, r1);   // kv 4j4, 4j4+1
            w[1] = pack2bf(r2, r3);   // kv 4j4+2, 4j4+3
            *(uint2v*)&Vt[vb][d0v + d][4 * j4] = w;
        }

        __syncthreads();   // barrier#1: staged tile visible

        // ---- swapped QK^T 32x32 on both kv-halves ----
        f32x16 sacc0, sacc1;
        #pragma unroll
        for (int i = 0; i < 16; ++i) { sacc0[i] = 0.f; sacc1[i] = 0.f; }
        #pragma unroll
        for (int ks = 0; ks < 8; ++ks) {
            short8 kf0 = *(const short8*)&Klds[l31][ks * 16 + hi * 8];
            short8 kf1 = *(const short8*)&Klds[32 + l31][ks * 16 + hi * 8];
            sacc0 = MFMA32(kf0, qf[ks], sacc0, 0, 0, 0);
            sacc1 = MFMA32(kf1, qf[ks], sacc1, 0, 0, 0);
        }

        __syncthreads();   // barrier#2: all K reads done -> next iter store safe

        // ---- issue next tile's loads: in flight across softmax+PV ----
        if (t < t1) LOAD_TILE(kv0 + KVB);

        // ---- lane-local online softmax over 64 kv (exp2 domain) ----
        const bool interior = (kv0 >= ctx + q0 - (WINDOW - QB)) &&
                              (kv0 + KVB - 1 <= ctx + q0);
        const int qpos = ctx + q0 + l31;
        float p2[2][16];
        #pragma unroll
        for (int m2 = 0; m2 < 2; ++m2) {
            #pragma unroll
            for (int r = 0; r < 16; ++r) {
                float x = (m2 == 0) ? sacc0[r] : sacc1[r];
                if (!interior) {
                    const int kpos = kv0 + m2 * 32 + (r & 3) + 4 * hi + 8 * (r >> 2);
                    const bool valid = (kpos <= qpos) && (qpos - kpos < WINDOW);
                    x = valid ? x : -INFINITY;
                }
                p2[m2][r] = x;
            }
        }
        // balanced-tree max (depth 5 instead of 32-deep serial chain)
        float tmax[16];
        #pragma unroll
        for (int r = 0; r < 16; ++r) tmax[r] = fmaxf(p2[0][r], p2[1][r]);
        #pragma unroll
        for (int s2 = 8; s2 > 0; s2 >>= 1)
            #pragma unroll
            for (int r = 0; r < 8; ++r)
                if (r < s2) tmax[r] = fmaxf(tmax[r], tmax[r + s2]);
        float rmax = xhalf_max(tmax[0]);

        const float mold = mrun;
        const bool defer = __all(rmax <= mold + 11.0f);   // THR ~ 8 nats in log2
        const float mnew = defer ? mold : fmaxf(mold, rmax);
        const float alpha = defer ? 1.0f
            : ((mold == -INFINITY) ? ((mnew == -INFINITY) ? 1.0f : 0.0f)
                                   : exp2f(mold - mnew));
        const bool dead = (mnew == -INFINITY);
        #pragma unroll
        for (int m2 = 0; m2 < 2; ++m2)
            #pragma unroll
            for (int r = 0; r < 16; ++r)
                p2[m2][r] = dead ? 0.f : exp2f(p2[m2][r] - mnew);
        // balanced-tree sum; lrun kept PER-HALF (merged once in epilogue —
        // valid: mnew/alpha are shared via rmax shuffle, l is additive)
        float ts[16];
        #pragma unroll
        for (int r = 0; r < 16; ++r) ts[r] = p2[0][r] + p2[1][r];
        #pragma unroll
        for (int s2 = 8; s2 > 0; s2 >>= 1)
            #pragma unroll
            for (int r = 0; r < 8; ++r)
                if (r < s2) ts[r] = ts[r] + ts[r + s2];
        lrun = lrun * alpha + ts[0];
        mrun = mnew;
        if (!defer) {
            #pragma unroll
            for (int dblk = 0; dblk < 4; ++dblk)
                oacc[dblk] = oacc[dblk] * alpha;
        }

        // ---- pack P -> B-frags; pre-selected single-shfl cross-half exchange ----
        short8 pb[2][2];
        #pragma unroll
        for (int m2 = 0; m2 < 2; ++m2) {
            unsigned int c0 = pack2bf(p2[m2][0],  p2[m2][1]);
            unsigned int c1 = pack2bf(p2[m2][2],  p2[m2][3]);
            unsigned int c2 = pack2bf(p2[m2][4],  p2[m2][5]);
            unsigned int c3 = pack2bf(p2[m2][6],  p2[m2][7]);
            unsigned int c4 = pack2bf(p2[m2][8],  p2[m2][9]);
            unsigned int c5 = pack2bf(p2[m2][10], p2[m2][11]);
            unsigned int c6 = pack2bf(p2[m2][12], p2[m2][13]);
            unsigned int c7 = pack2bf(p2[m2][14], p2[m2][15]);
            unsigned int s0 = hi ? c0 : c2;
            unsigned int s1 = hi ? c1 : c3;
            unsigned int s2 = hi ? c4 : c6;
            unsigned int s3 = hi ? c5 : c7;
            unsigned int r0 = (unsigned int)__shfl_xor((int)s0, 32);
            unsigned int r1 = (unsigned int)__shfl_xor((int)s1, 32);
            unsigned int r2 = (unsigned int)__shfl_xor((int)s2, 32);
            unsigned int r3 = (unsigned int)__shfl_xor((int)s3, 32);
            uint4v u0, u1;
            u0[0] = hi ? r0 : c0;
            u0[1] = hi ? r1 : c1;
            u0[2] = hi ? c2 : r0;
            u0[3] = hi ? c3 : r1;
            u1[0] = hi ? r2 : c4;
            u1[1] = hi ? r3 : c5;
            u1[2] = hi ? c6 : r2;
            u1[3] = hi ? c7 : r3;
            pb[m2][0] = __builtin_bit_cast(short8, u0);   // kv m2*32 + 0..15
            pb[m2][1] = __builtin_bit_cast(short8, u1);   // kv m2*32 + 16..31
        }

        // ---- PV 32x32: O^T += mfma32(A=V^T, B=P^T), both kv-halves ----
        #pragma unroll
        for (int m2 = 0; m2 < 2; ++m2) {
            #pragma unroll
            for (int dblk = 0; dblk < 4; ++dblk) {
                short8 vf0 = *(const short8*)&Vt[vb][dblk * 32 + l31][m2 * 32 + hi * 8];
                short8 vf1 = *(const short8*)&Vt[vb][dblk * 32 + l31][m2 * 32 + 16 + hi * 8];
                oacc[dblk] = MFMA32(vf0, pb[m2][0], oacc[dblk], 0, 0, 0);
                oacc[dblk] = MFMA32(vf1, pb[m2][1], oacc[dblk], 0, 0, 0);
            }
        }
    }
#undef LOAD_TILE
#undef LOAD_V
#undef LOAD_K_HALF

    // ---- epilogue: merge per-half l, lane-local normalize, b128 stores ----
    {
        const float ltot = lrun + __shfl_xor(lrun, 32);
        const float inv = 1.0f / ltot;
        float* orow = outg + ((size_t)(qstart + q0 + l31) * HQN + hq) * HD;
        #pragma unroll
        for (int dblk = 0; dblk < 4; ++dblk) {
            #pragma unroll
            for (int rq = 0; rq < 4; ++rq) {
                floatx4 o;
                o[0] = oacc[dblk][4 * rq + 0] * inv;
                o[1] = oacc[dblk][4 * rq + 1] * inv;
                o[2] = oacc[dblk][4 * rq + 2] * inv;
                o[3] = oacc[dblk][4 * rq + 3] * inv;
                *(floatx4*)(orow + dblk * 32 + 8 * rq + 4 * hi) = o;
            }
        }
    }
}

extern "C" void kernel_launch(void* const* d_in, const int* in_sizes, int n_in,
                              void* d_out, int out_size, void* d_ws, size_t ws_size,
                              hipStream_t stream) {
    const float* q  = (const float*)d_in[0];
    const float* k  = (const float*)d_in[1];
    const float* v  = (const float*)d_in[2];
    const int* btp  = (const int*)d_in[3];
    const int* sl   = (const int*)d_in[4];
    const int* qs   = (const int*)d_in[5];
    float* out      = (float*)d_out;

    attn_fwd<<<dim3(NSEQ * HKVN * 8), 256, 0, stream>>>(q, k, v, btp, sl, qs, out);
}